// Round 9
// baseline (253.565 us; speedup 1.0000x reference)
//
#include <hip/hip_runtime.h>

#define INDIM 256
#define HID 128
#define OUTD 64
#define BINSHIFT 8
#define MAXBIN 256   // supports M <= 65536

typedef _Float16 f16x8 __attribute__((ext_vector_type(8)));
typedef float    f32x4 __attribute__((ext_vector_type(4)));

// =============== pass 1: per-wg partial histogram (no atomics, no pre-zero) + weight prep ===============
__global__ __launch_bounds__(256) void k_hist_prep(const int* __restrict__ dst, int* __restrict__ hist_part,
                                                   int E,
                                                   const float* __restrict__ W1, const float* __restrict__ W2,
                                                   _Float16* __restrict__ W1t, _Float16* __restrict__ W2t) {
    __shared__ int h[MAXBIN];
    int tid = threadIdx.x;
    h[tid] = 0;
    __syncthreads();
    int base = blockIdx.x * 4096;
#pragma unroll
    for (int i = 0; i < 16; i++) {
        int e = base + i * 256 + tid;
        if (e < E) atomicAdd(&h[dst[e] >> BINSHIFT], 1);
    }
    __syncthreads();
    hist_part[blockIdx.x * MAXBIN + tid] = h[tid];

    // fused weight transpose/convert (needs grid*256 >= 40960; E/4096 wgs is plenty)
    constexpr int NW1 = HID * INDIM;   // 32768
    constexpr int NW2 = OUTD * HID;    // 8192
    int id = blockIdx.x * 256 + tid;
    if (id < NW1) {
        int n = id / INDIM, k = id % INDIM;
        W1t[id] = (_Float16)W1[k * HID + n];
    } else if (id < NW1 + NW2) {
        int j = id - NW1;
        int n = j / HID, k = j % HID;
        W2t[j] = (_Float16)W2[k * OUTD + n];
    }
}

// =============== pass 2: reduce partials + exclusive scan (1 wg) ===============
__global__ __launch_bounds__(256) void k_scan(const int* __restrict__ hist_part, int NWH,
                                              int* __restrict__ bin_start, int* __restrict__ bin_cursor,
                                              int* __restrict__ row_start, int NBIN, int M, int E) {
    __shared__ int s[256];
    int tid = threadIdx.x;
    int v = 0;
    for (int w = 0; w < NWH; w++) v += hist_part[w * MAXBIN + tid];
    if (tid >= NBIN) v = 0;
    s[tid] = v;
    __syncthreads();
#pragma unroll
    for (int off = 1; off < 256; off <<= 1) {
        int t = (tid >= off) ? s[tid - off] : 0;
        __syncthreads();
        s[tid] += t;
        __syncthreads();
    }
    if (tid < NBIN) {
        int excl = s[tid] - v;
        bin_start[tid] = excl;
        bin_cursor[tid] = excl;
    }
    if (tid == 0) {
        bin_start[NBIN] = E;
        row_start[M] = E;
    }
}

// =============== pass 3: scatter packed (src<<8 | dst&255) into bin runs ===============
__global__ __launch_bounds__(256) void k_binfill(const int* __restrict__ src, const int* __restrict__ dst,
                                                 int* __restrict__ bin_cursor, int* __restrict__ binned, int E) {
    __shared__ int h[MAXBIN];
    __shared__ int rb[MAXBIN];
    int tid = threadIdx.x;
    h[tid] = 0;
    __syncthreads();
    int base = blockIdx.x * 2048;
    int ep[8], eb[8], rk[8];
#pragma unroll
    for (int i = 0; i < 8; i++) {
        int e = base + i * 256 + tid;
        if (e < E) {
            int s = src[e], d = dst[e];
            ep[i] = (s << 8) | (d & 255);
            eb[i] = d >> BINSHIFT;
            rk[i] = atomicAdd(&h[eb[i]], 1);
        } else {
            eb[i] = -1;
        }
    }
    __syncthreads();
    int c = h[tid];
    if (c) rb[tid] = atomicAdd(&bin_cursor[tid], c);
    __syncthreads();
#pragma unroll
    for (int i = 0; i < 8; i++) {
        if (eb[i] >= 0) binned[rb[eb[i]] + rk[i]] = ep[i];
    }
}

// =============== pass 4: per-bin CSR finalize (row_start, dinv, edge_src) ===============
__global__ __launch_bounds__(256) void k_csr(const int* __restrict__ binned, const int* __restrict__ bin_start,
                                             int* __restrict__ row_start, float* __restrict__ dinv,
                                             int* __restrict__ edge_src, int M) {
    __shared__ int cnt[256];
    __shared__ int s[256];
    __shared__ int cur[256];
    int b = blockIdx.x, tid = threadIdx.x;
    int beg = bin_start[b], end = bin_start[b + 1];
    cnt[tid] = 0;
    __syncthreads();
    for (int i = beg + tid; i < end; i += 256) {
        atomicAdd(&cnt[binned[i] & 255], 1);
    }
    __syncthreads();
    int c = cnt[tid];
    s[tid] = c;
    __syncthreads();
#pragma unroll
    for (int off = 1; off < 256; off <<= 1) {
        int t = (tid >= off) ? s[tid - off] : 0;
        __syncthreads();
        s[tid] += t;
        __syncthreads();
    }
    int start = beg + s[tid] - c;
    int node = (b << BINSHIFT) + tid;
    if (node < M) {
        row_start[node] = start;
        dinv[node] = rsqrtf(1.0f + (float)c);
    }
    cur[tid] = start;
    __syncthreads();
    for (int i = beg + tid; i < end; i += 256) {
        int p = binned[i];
        int pos = atomicAdd(&cur[p & 255], 1);
        edge_src[pos] = p >> 8;
    }
}

// =============== GEMM1: fp32 X @ fp16 W1t -> pre-scaled fp16 xw16 ===============
__global__ __launch_bounds__(256) void k_gemm1(
    const float* __restrict__ X, const _Float16* __restrict__ Wt,
    const float* __restrict__ dinv, _Float16* __restrict__ XW16, int M)
{
    constexpr int BM = 64;
    constexpr int BK = 32;
    constexpr int BN = HID;
    constexpr int NT = BN / 16;
    constexpr int LDK = BK + 8;   // 80 B stride

    __shared__ __align__(16) _Float16 As[BM][LDK];
    __shared__ __align__(16) _Float16 Bs[BN][LDK];

    const int tid  = threadIdx.x;
    const int wave = tid >> 6;
    const int lane = tid & 63;
    const int m    = lane & 15;
    const int q    = lane >> 4;
    const int rb   = blockIdx.x * BM;

    f32x4 acc[NT];
#pragma unroll
    for (int t = 0; t < NT; t++) acc[t] = (f32x4){0.f, 0.f, 0.f, 0.f};

    for (int kt = 0; kt < INDIM; kt += BK) {
        if (kt) __syncthreads();
#pragma unroll
        for (int i = 0; i < BM * 8 / 256; i++) {
            int ch  = tid + i * 256;
            int row = ch >> 3;
            int c4  = ch & 7;
            int gr  = rb + row;
            float4 v = make_float4(0.f, 0.f, 0.f, 0.f);
            if (gr < M) v = *(const float4*)(X + (long)gr * INDIM + kt + c4 * 4);
            _Float16* p = &As[row][c4 * 4];
            p[0] = (_Float16)v.x; p[1] = (_Float16)v.y;
            p[2] = (_Float16)v.z; p[3] = (_Float16)v.w;
        }
#pragma unroll
        for (int i = 0; i < BN * 8 / 256; i++) {
            int ch = tid + i * 256;
            int n  = ch >> 3;
            int c4 = ch & 7;
            *(ushort4*)(&Bs[n][c4 * 4]) =
                *(const ushort4*)(Wt + (long)n * INDIM + kt + c4 * 4);
        }
        __syncthreads();

        f16x8 af = *(const f16x8*)(&As[wave * 16 + m][q * 8]);
#pragma unroll
        for (int t = 0; t < NT; t++) {
            f16x8 bf = *(const f16x8*)(&Bs[t * 16 + m][q * 8]);
            acc[t] = __builtin_amdgcn_mfma_f32_16x16x32_f16(af, bf, acc[t], 0, 0, 0);
        }
    }

    int row0 = rb + wave * 16 + q * 4;
#pragma unroll
    for (int r = 0; r < 4; r++) {
        int row = row0 + r;
        if (row < M) {
            float di = dinv[row];
#pragma unroll
            for (int t = 0; t < NT; t++) {
                XW16[(long)row * BN + t * 16 + m] = (_Float16)(acc[t][r] * di);
            }
        }
    }
}

// =============== FUSED: agg1 (gather+tanh -> LDS) + gemm2 (LDS @ W2t -> hw16) ===============
// Phase A: h[n] = tanh(b1 + dinv[n]*(xw16[n] + sum_e xw16[src_e]))   (64 rows in LDS)
// Phase B: hw16[n] = fp16((h @ W2)[n] * dinv[n])                     (MFMA from LDS)
__global__ __launch_bounds__(256) void k_agg1_gemm2(
    const int* __restrict__ row_start, const int* __restrict__ edge_src,
    const _Float16* __restrict__ xw16, const float* __restrict__ b1,
    const float* __restrict__ dinv, const _Float16* __restrict__ W2t,
    _Float16* __restrict__ hw16, int M)
{
    constexpr int LDH = HID + 8;   // 272 B row stride (2-way-free pattern like gemm)
    __shared__ __align__(16) _Float16 Hs[64][LDH];

    const int tid = threadIdx.x;
    const int rb  = blockIdx.x * 64;

    // ---- Phase A: 4 sub-rounds x 16 nodes; 16 lanes/node x 8 halfs ----
#pragma unroll
    for (int sub = 0; sub < 4; sub++) {
        int nl = sub * 16 + (tid >> 4);
        int n  = rb + nl;
        int c  = tid & 15;
        f16x8 o;
        if (n < M) {
            int beg = row_start[n], end = row_start[n + 1];
            f16x8 self = *(const f16x8*)(xw16 + (long)n * HID + c * 8);
            float acc[8], acc2[8];
#pragma unroll
            for (int k = 0; k < 8; k++) { acc[k] = (float)self[k]; acc2[k] = 0.f; }
            int j = beg;
            for (; j + 3 < end; j += 4) {
                int s0 = edge_src[j],     s1 = edge_src[j + 1];
                int s2 = edge_src[j + 2], s3 = edge_src[j + 3];
                f16x8 v0 = *(const f16x8*)(xw16 + (long)s0 * HID + c * 8);
                f16x8 v1 = *(const f16x8*)(xw16 + (long)s1 * HID + c * 8);
                f16x8 v2 = *(const f16x8*)(xw16 + (long)s2 * HID + c * 8);
                f16x8 v3 = *(const f16x8*)(xw16 + (long)s3 * HID + c * 8);
#pragma unroll
                for (int k = 0; k < 8; k++) {
                    acc[k]  += (float)v0[k] + (float)v1[k];
                    acc2[k] += (float)v2[k] + (float)v3[k];
                }
            }
            for (; j < end; j++) {
                int s = edge_src[j];
                f16x8 v = *(const f16x8*)(xw16 + (long)s * HID + c * 8);
#pragma unroll
                for (int k = 0; k < 8; k++) acc[k] += (float)v[k];
            }
            float di = dinv[n];
#pragma unroll
            for (int k = 0; k < 8; k++)
                o[k] = (_Float16)tanhf(b1[c * 8 + k] + di * (acc[k] + acc2[k]));
        } else {
#pragma unroll
            for (int k = 0; k < 8; k++) o[k] = (_Float16)0.f;
        }
        *(f16x8*)(&Hs[nl][c * 8]) = o;
    }
    __syncthreads();

    // ---- Phase B: 64x64x128 MFMA from LDS; B-fragments direct from L2-hot W2t ----
    const int wave = tid >> 6;
    const int lane = tid & 63;
    const int m    = lane & 15;
    const int q    = lane >> 4;
    constexpr int NT = OUTD / 16;   // 4

    f32x4 acc[NT];
#pragma unroll
    for (int t = 0; t < NT; t++) acc[t] = (f32x4){0.f, 0.f, 0.f, 0.f};

#pragma unroll
    for (int kt = 0; kt < HID; kt += 32) {
        f16x8 af = *(const f16x8*)(&Hs[wave * 16 + m][kt + q * 8]);
#pragma unroll
        for (int t = 0; t < NT; t++) {
            f16x8 bf = *(const f16x8*)(W2t + (long)(t * 16 + m) * HID + kt + q * 8);
            acc[t] = __builtin_amdgcn_mfma_f32_16x16x32_f16(af, bf, acc[t], 0, 0, 0);
        }
    }

    int row0 = rb + wave * 16 + q * 4;
#pragma unroll
    for (int r = 0; r < 4; r++) {
        int row = row0 + r;
        if (row < M) {
            float di = dinv[row];
#pragma unroll
            for (int t = 0; t < NT; t++) {
                hw16[(long)row * OUTD + t * 16 + m] = (_Float16)(acc[t][r] * di);
            }
        }
    }
}

// =============== agg2: gather hw16 -> out (fp32) ===============
__global__ __launch_bounds__(256) void k_agg2(const int* __restrict__ row_start,
                                              const int* __restrict__ edge_src,
                                              const _Float16* __restrict__ feat,
                                              const float* __restrict__ b2,
                                              const float* __restrict__ dinv,
                                              float* __restrict__ out, int M) {
    constexpr int F = OUTD;
    constexpr int LPN = F / 8;          // 8 lanes per node
    int n = blockIdx.x * (256 / LPN) + threadIdx.x / LPN;
    int c = threadIdx.x % LPN;
    if (n >= M) return;
    int beg = row_start[n], end = row_start[n + 1];

    f16x8 self = *(const f16x8*)(feat + (long)n * F + c * 8);
    float acc[8], acc2[8];
#pragma unroll
    for (int k = 0; k < 8; k++) { acc[k] = (float)self[k]; acc2[k] = 0.f; }

    int j = beg;
    for (; j + 3 < end; j += 4) {
        int s0 = edge_src[j],     s1 = edge_src[j + 1];
        int s2 = edge_src[j + 2], s3 = edge_src[j + 3];
        f16x8 v0 = *(const f16x8*)(feat + (long)s0 * F + c * 8);
        f16x8 v1 = *(const f16x8*)(feat + (long)s1 * F + c * 8);
        f16x8 v2 = *(const f16x8*)(feat + (long)s2 * F + c * 8);
        f16x8 v3 = *(const f16x8*)(feat + (long)s3 * F + c * 8);
#pragma unroll
        for (int k = 0; k < 8; k++) {
            acc[k]  += (float)v0[k] + (float)v1[k];
            acc2[k] += (float)v2[k] + (float)v3[k];
        }
    }
    for (; j < end; j++) {
        int s = edge_src[j];
        f16x8 v = *(const f16x8*)(feat + (long)s * F + c * 8);
#pragma unroll
        for (int k = 0; k < 8; k++) acc[k] += (float)v[k];
    }

    float di = dinv[n];
#pragma unroll
    for (int k = 0; k < 8; k++) acc[k] = b2[c * 8 + k] + di * (acc[k] + acc2[k]);

    f32x4 o0 = {acc[0], acc[1], acc[2], acc[3]};
    f32x4 o1 = {acc[4], acc[5], acc[6], acc[7]};
    float* p = out + (long)n * F + c * 8;
    __builtin_nontemporal_store(o0, (f32x4*)p);
    __builtin_nontemporal_store(o1, (f32x4*)(p + 4));
}

extern "C" void kernel_launch(void* const* d_in, const int* in_sizes, int n_in,
                              void* d_out, int out_size, void* d_ws, size_t ws_size,
                              hipStream_t stream) {
    const float* x  = (const float*)d_in[0];
    const int*   ei = (const int*)d_in[1];
    const float* W1 = (const float*)d_in[2];
    const float* b1 = (const float*)d_in[3];
    const float* W2 = (const float*)d_in[4];
    const float* b2 = (const float*)d_in[5];
    float* out = (float*)d_out;

    const int M = in_sizes[0] / INDIM;   // 50000
    const int E = in_sizes[1] / 2;       // 800000
    const int* srcp = ei;
    const int* dstp = ei + E;

    const int Mp   = (M + 63) & ~63;
    const int NBIN = (M + 255) >> BINSHIFT;  // 196
    int NWH = (E + 4095) / 4096;             // hist wgs
    if (NWH < 161) NWH = 161;                // ensure weight prep covers 41K elements
    const int NWF = (E + 2047) / 2048;       // binfill wgs

    // workspace layout
    float*     dinv       = (float*)d_ws;
    int*       row_start  = (int*)(dinv + Mp);            // [M+1] <= Mp
    int*       bin_start  = row_start + Mp;               // [NBIN+1] padded 258
    int*       bin_cursor = bin_start + 258;              // [MAXBIN]
    int*       hist_part  = bin_cursor + MAXBIN;          // [NWH][MAXBIN]
    _Float16*  W1t        = (_Float16*)(hist_part + (long)NWH * MAXBIN);  // [HID][INDIM]
    _Float16*  W2t        = W1t + HID * INDIM;                            // [OUTD][HID]
    int*       binned     = (int*)(W2t + OUTD * HID);                     // [E] packed
    int*       edge_src   = binned + E;                                   // [E]
    _Float16*  xw16       = (_Float16*)(edge_src + E);                    // [M][HID] pre-scaled
    _Float16*  hw16       = xw16 + (long)M * HID;                         // [M][OUTD] pre-scaled

    // ---- build (4 launches, no memset, no global atomics in hist) ----
    k_hist_prep<<<NWH, 256, 0, stream>>>(dstp, hist_part, E, W1, W2, W1t, W2t);
    k_scan<<<1, 256, 0, stream>>>(hist_part, NWH, bin_start, bin_cursor, row_start, NBIN, M, E);
    k_binfill<<<NWF, 256, 0, stream>>>(srcp, dstp, bin_cursor, binned, E);
    k_csr<<<NBIN, 256, 0, stream>>>(binned, bin_start, row_start, dinv, edge_src, M);

    // ---- layer 1 GEMM ----
    k_gemm1<<<(M + 63) / 64, 256, 0, stream>>>(x, W1t, dinv, xw16, M);

    // ---- fused agg1 + gemm2 (h never touches HBM) ----
    k_agg1_gemm2<<<(M + 63) / 64, 256, 0, stream>>>(row_start, edge_src, xw16, b1, dinv, W2t, hw16, M);

    // ---- layer 2 aggregation ----
    k_agg2<<<(M + 31) / 32, 256, 0, stream>>>(row_start, edge_src, hw16, b2, dinv, out, M);
}

// Round 10
// 231.783 us; speedup vs baseline: 1.0940x; 1.0940x over previous
//
#include <hip/hip_runtime.h>

#define INDIM 256
#define HID 128
#define OUTD 64
#define BINSHIFT 8
#define MAXBIN 256   // supports M <= 65536

typedef _Float16 f16x8 __attribute__((ext_vector_type(8)));
typedef float    f32x4 __attribute__((ext_vector_type(4)));

// =============== pass 1: per-wg partial histogram (no global atomics) + weight prep ===============
__global__ __launch_bounds__(256) void k_hist_prep(const int* __restrict__ dst, int* __restrict__ hist_part,
                                                   int E,
                                                   const float* __restrict__ W1, const float* __restrict__ W2,
                                                   _Float16* __restrict__ W1t, _Float16* __restrict__ W2t) {
    __shared__ int h[MAXBIN];
    int tid = threadIdx.x;
    h[tid] = 0;
    __syncthreads();
    int base = blockIdx.x * 4096;
#pragma unroll
    for (int i = 0; i < 16; i++) {
        int e = base + i * 256 + tid;
        if (e < E) atomicAdd(&h[dst[e] >> BINSHIFT], 1);
    }
    __syncthreads();
    hist_part[blockIdx.x * MAXBIN + tid] = h[tid];

    // fused weight transpose/convert
    constexpr int NW1 = HID * INDIM;   // 32768
    constexpr int NW2 = OUTD * HID;    // 8192
    int id = blockIdx.x * 256 + tid;
    if (id < NW1) {
        int n = id / INDIM, k = id % INDIM;
        W1t[id] = (_Float16)W1[k * HID + n];
    } else if (id < NW1 + NW2) {
        int j = id - NW1;
        int n = j / HID, k = j % HID;
        W2t[j] = (_Float16)W2[k * OUTD + n];
    }
}

// =============== pass 2: reduce partials (4-way MLP) + exclusive scan (1 wg) ===============
__global__ __launch_bounds__(256) void k_scan(const int* __restrict__ hist_part, int NWH,
                                              int* __restrict__ bin_start, int* __restrict__ bin_cursor,
                                              int* __restrict__ row_start, int NBIN, int M, int E) {
    __shared__ int s[256];
    int tid = threadIdx.x;
    int a0 = 0, a1 = 0, a2 = 0, a3 = 0;
    int w = 0;
    for (; w + 3 < NWH; w += 4) {
        a0 += hist_part[(w + 0) * MAXBIN + tid];
        a1 += hist_part[(w + 1) * MAXBIN + tid];
        a2 += hist_part[(w + 2) * MAXBIN + tid];
        a3 += hist_part[(w + 3) * MAXBIN + tid];
    }
    for (; w < NWH; w++) a0 += hist_part[w * MAXBIN + tid];
    int v = (a0 + a1) + (a2 + a3);
    if (tid >= NBIN) v = 0;
    s[tid] = v;
    __syncthreads();
#pragma unroll
    for (int off = 1; off < 256; off <<= 1) {
        int t = (tid >= off) ? s[tid - off] : 0;
        __syncthreads();
        s[tid] += t;
        __syncthreads();
    }
    if (tid < NBIN) {
        int excl = s[tid] - v;
        bin_start[tid] = excl;
        bin_cursor[tid] = excl;
    }
    if (tid == 0) {
        bin_start[NBIN] = E;
        row_start[M] = E;
    }
}

// =============== pass 3: scatter packed (src<<8 | dst&255) into bin runs ===============
__global__ __launch_bounds__(256) void k_binfill(const int* __restrict__ src, const int* __restrict__ dst,
                                                 int* __restrict__ bin_cursor, int* __restrict__ binned, int E) {
    __shared__ int h[MAXBIN];
    __shared__ int rb[MAXBIN];
    int tid = threadIdx.x;
    h[tid] = 0;
    __syncthreads();
    int base = blockIdx.x * 2048;
    int ep[8], eb[8], rk[8];
#pragma unroll
    for (int i = 0; i < 8; i++) {
        int e = base + i * 256 + tid;
        if (e < E) {
            int s = src[e], d = dst[e];
            ep[i] = (s << 8) | (d & 255);
            eb[i] = d >> BINSHIFT;
            rk[i] = atomicAdd(&h[eb[i]], 1);
        } else {
            eb[i] = -1;
        }
    }
    __syncthreads();
    int c = h[tid];
    if (c) rb[tid] = atomicAdd(&bin_cursor[tid], c);
    __syncthreads();
#pragma unroll
    for (int i = 0; i < 8; i++) {
        if (eb[i] >= 0) binned[rb[eb[i]] + rk[i]] = ep[i];
    }
}

// =============== pass 4: per-bin CSR finalize (row_start, dinv, edge_src) ===============
__global__ __launch_bounds__(256) void k_csr(const int* __restrict__ binned, const int* __restrict__ bin_start,
                                             int* __restrict__ row_start, float* __restrict__ dinv,
                                             int* __restrict__ edge_src, int M) {
    __shared__ int cnt[256];
    __shared__ int s[256];
    __shared__ int cur[256];
    int b = blockIdx.x, tid = threadIdx.x;
    int beg = bin_start[b], end = bin_start[b + 1];
    cnt[tid] = 0;
    __syncthreads();
    for (int i = beg + tid; i < end; i += 256) {
        atomicAdd(&cnt[binned[i] & 255], 1);
    }
    __syncthreads();
    int c = cnt[tid];
    s[tid] = c;
    __syncthreads();
#pragma unroll
    for (int off = 1; off < 256; off <<= 1) {
        int t = (tid >= off) ? s[tid - off] : 0;
        __syncthreads();
        s[tid] += t;
        __syncthreads();
    }
    int start = beg + s[tid] - c;
    int node = (b << BINSHIFT) + tid;
    if (node < M) {
        row_start[node] = start;
        dinv[node] = rsqrtf(1.0f + (float)c);
    }
    cur[tid] = start;
    __syncthreads();
    for (int i = beg + tid; i < end; i += 256) {
        int p = binned[i];
        int pos = atomicAdd(&cur[p & 255], 1);
        edge_src[pos] = p >> 8;
    }
}

// =============== MFMA fp16 GEMM, pre-scaled fp16 output (row-major) ===============
// X[M][K] (fp32 or fp16), Wt[BN][K] fp16. XW16[row] = fp16((X@W)[row] * dinv[row]).
template <int BN, int K, typename AT>
__global__ __launch_bounds__(256) void k_gemm_mfma(
    const AT* __restrict__ X, const _Float16* __restrict__ Wt,
    const float* __restrict__ dinv, _Float16* __restrict__ XW16, int M)
{
    constexpr int BM = 64;
    constexpr int BK = 32;
    constexpr int NT = BN / 16;
    constexpr int LDK = BK + 8;   // 40 halfs = 80 B stride, 16B-aligned

    __shared__ __align__(16) _Float16 As[BM][LDK];
    __shared__ __align__(16) _Float16 Bs[BN][LDK];

    const int tid  = threadIdx.x;
    const int wave = tid >> 6;
    const int lane = tid & 63;
    const int m    = lane & 15;
    const int q    = lane >> 4;
    const int rb   = blockIdx.x * BM;

    f32x4 acc[NT];
#pragma unroll
    for (int t = 0; t < NT; t++) acc[t] = (f32x4){0.f, 0.f, 0.f, 0.f};

    for (int kt = 0; kt < K; kt += BK) {
        if (kt) __syncthreads();
        if constexpr (sizeof(AT) == 4) {
#pragma unroll
            for (int i = 0; i < BM * 8 / 256; i++) {
                int ch  = tid + i * 256;
                int row = ch >> 3;
                int c4  = ch & 7;
                int gr  = rb + row;
                float4 v = make_float4(0.f, 0.f, 0.f, 0.f);
                if (gr < M) v = *(const float4*)((const float*)X + (long)gr * K + kt + c4 * 4);
                _Float16* p = &As[row][c4 * 4];
                p[0] = (_Float16)v.x; p[1] = (_Float16)v.y;
                p[2] = (_Float16)v.z; p[3] = (_Float16)v.w;
            }
        } else {
            int row = tid >> 2;
            int c8  = tid & 3;
            int gr  = rb + row;
            uint4 v = make_uint4(0u, 0u, 0u, 0u);
            if (gr < M) v = *(const uint4*)((const _Float16*)X + (long)gr * K + kt + c8 * 8);
            *(uint4*)(&As[row][c8 * 8]) = v;
        }
#pragma unroll
        for (int i = 0; i < BN * 8 / 256; i++) {
            int ch = tid + i * 256;
            int n  = ch >> 3;
            int c4 = ch & 7;
            *(ushort4*)(&Bs[n][c4 * 4]) =
                *(const ushort4*)(Wt + (long)n * K + kt + c4 * 4);
        }
        __syncthreads();

        f16x8 af = *(const f16x8*)(&As[wave * 16 + m][q * 8]);
#pragma unroll
        for (int t = 0; t < NT; t++) {
            f16x8 bf = *(const f16x8*)(&Bs[t * 16 + m][q * 8]);
            acc[t] = __builtin_amdgcn_mfma_f32_16x16x32_f16(af, bf, acc[t], 0, 0, 0);
        }
    }

    int row0 = rb + wave * 16 + q * 4;
#pragma unroll
    for (int r = 0; r < 4; r++) {
        int row = row0 + r;
        if (row < M) {
            float di = dinv[row];
#pragma unroll
            for (int t = 0; t < NT; t++) {
                XW16[(long)row * BN + t * 16 + m] = (_Float16)(acc[t][r] * di);
            }
        }
    }
}

// =============== CSR gather-aggregation (pre-scaled fp16 table, 8x unrolled) ===============
// out[n] = act(bias + dinv[n] * (feat[n] + sum_{e in(n)} feat[src_e]))
template <int F, bool TANH, typename OutT>
__global__ __launch_bounds__(256) void k_agg_csr(const int* __restrict__ row_start,
                                                 const int* __restrict__ edge_src,
                                                 const _Float16* __restrict__ feat,
                                                 const float* __restrict__ bias,
                                                 const float* __restrict__ dinv,
                                                 OutT* __restrict__ out, int M) {
    constexpr int LPN = F / 8;          // lanes per node, 8 halfs (16B) each
    constexpr int NPB = 256 / LPN;
    int n = blockIdx.x * NPB + threadIdx.x / LPN;
    int c = threadIdx.x % LPN;
    if (n >= M) return;
    int beg = row_start[n], end = row_start[n + 1];

    f16x8 self = *(const f16x8*)(feat + (long)n * F + c * 8);
    float a0[8], a1[8], a2[8], a3[8];
#pragma unroll
    for (int k = 0; k < 8; k++) { a0[k] = (float)self[k]; a1[k] = 0.f; a2[k] = 0.f; a3[k] = 0.f; }

    int j = beg;
    for (; j + 7 < end; j += 8) {
        int s0 = edge_src[j],     s1 = edge_src[j + 1];
        int s2 = edge_src[j + 2], s3 = edge_src[j + 3];
        int s4 = edge_src[j + 4], s5 = edge_src[j + 5];
        int s6 = edge_src[j + 6], s7 = edge_src[j + 7];
        f16x8 v0 = *(const f16x8*)(feat + (long)s0 * F + c * 8);
        f16x8 v1 = *(const f16x8*)(feat + (long)s1 * F + c * 8);
        f16x8 v2 = *(const f16x8*)(feat + (long)s2 * F + c * 8);
        f16x8 v3 = *(const f16x8*)(feat + (long)s3 * F + c * 8);
        f16x8 v4 = *(const f16x8*)(feat + (long)s4 * F + c * 8);
        f16x8 v5 = *(const f16x8*)(feat + (long)s5 * F + c * 8);
        f16x8 v6 = *(const f16x8*)(feat + (long)s6 * F + c * 8);
        f16x8 v7 = *(const f16x8*)(feat + (long)s7 * F + c * 8);
#pragma unroll
        for (int k = 0; k < 8; k++) {
            a0[k] += (float)v0[k] + (float)v1[k];
            a1[k] += (float)v2[k] + (float)v3[k];
            a2[k] += (float)v4[k] + (float)v5[k];
            a3[k] += (float)v6[k] + (float)v7[k];
        }
    }
    for (; j + 3 < end; j += 4) {
        int s0 = edge_src[j],     s1 = edge_src[j + 1];
        int s2 = edge_src[j + 2], s3 = edge_src[j + 3];
        f16x8 v0 = *(const f16x8*)(feat + (long)s0 * F + c * 8);
        f16x8 v1 = *(const f16x8*)(feat + (long)s1 * F + c * 8);
        f16x8 v2 = *(const f16x8*)(feat + (long)s2 * F + c * 8);
        f16x8 v3 = *(const f16x8*)(feat + (long)s3 * F + c * 8);
#pragma unroll
        for (int k = 0; k < 8; k++) {
            a0[k] += (float)v0[k] + (float)v1[k];
            a1[k] += (float)v2[k] + (float)v3[k];
        }
    }
    for (; j < end; j++) {
        int s = edge_src[j];
        f16x8 v = *(const f16x8*)(feat + (long)s * F + c * 8);
#pragma unroll
        for (int k = 0; k < 8; k++) a0[k] += (float)v[k];
    }

    float di = dinv[n];
    float acc[8];
#pragma unroll
    for (int k = 0; k < 8; k++)
        acc[k] = bias[c * 8 + k] + di * ((a0[k] + a1[k]) + (a2[k] + a3[k]));
    if (TANH) {
#pragma unroll
        for (int k = 0; k < 8; k++) acc[k] = tanhf(acc[k]);
    }
    if constexpr (sizeof(OutT) == 2) {
        f16x8 o;
#pragma unroll
        for (int k = 0; k < 8; k++) o[k] = (_Float16)acc[k];
        __builtin_nontemporal_store(o, (f16x8*)((_Float16*)out + (long)n * F + c * 8));
    } else {
        f32x4 o0 = {acc[0], acc[1], acc[2], acc[3]};
        f32x4 o1 = {acc[4], acc[5], acc[6], acc[7]};
        float* p = (float*)out + (long)n * F + c * 8;
        __builtin_nontemporal_store(o0, (f32x4*)p);
        __builtin_nontemporal_store(o1, (f32x4*)(p + 4));
    }
}

extern "C" void kernel_launch(void* const* d_in, const int* in_sizes, int n_in,
                              void* d_out, int out_size, void* d_ws, size_t ws_size,
                              hipStream_t stream) {
    const float* x  = (const float*)d_in[0];
    const int*   ei = (const int*)d_in[1];
    const float* W1 = (const float*)d_in[2];
    const float* b1 = (const float*)d_in[3];
    const float* W2 = (const float*)d_in[4];
    const float* b2 = (const float*)d_in[5];
    float* out = (float*)d_out;

    const int M = in_sizes[0] / INDIM;   // 50000
    const int E = in_sizes[1] / 2;       // 800000
    const int* srcp = ei;
    const int* dstp = ei + E;

    const int Mp   = (M + 63) & ~63;
    const int NBIN = (M + 255) >> BINSHIFT;  // 196
    int NWH = (E + 4095) / 4096;             // hist wgs
    if (NWH < 161) NWH = 161;                // weight prep needs >= 161 wgs
    const int NWF = (E + 2047) / 2048;       // binfill wgs

    // workspace layout
    float*     dinv       = (float*)d_ws;
    int*       row_start  = (int*)(dinv + Mp);            // [M+1] <= Mp
    int*       bin_start  = row_start + Mp;               // [NBIN+1] padded 258
    int*       bin_cursor = bin_start + 258;              // [MAXBIN]
    int*       hist_part  = bin_cursor + MAXBIN;          // [NWH][MAXBIN]
    _Float16*  W1t        = (_Float16*)(hist_part + (long)NWH * MAXBIN);  // [HID][INDIM]
    _Float16*  W2t        = W1t + HID * INDIM;                            // [OUTD][HID]
    int*       binned     = (int*)(W2t + OUTD * HID);                     // [E] packed
    int*       edge_src   = binned + E;                                   // [E]
    _Float16*  xw16       = (_Float16*)(edge_src + E);                    // [M][HID] pre-scaled
    _Float16*  h16        = xw16 + (long)M * HID;                         // [M][HID]
    _Float16*  hw16       = xw16;                                         // alias: xw dead after agg1

    // ---- build (4 launches, no memset, no global atomics in hist) ----
    k_hist_prep<<<NWH, 256, 0, stream>>>(dstp, hist_part, E, W1, W2, W1t, W2t);
    k_scan<<<1, 256, 0, stream>>>(hist_part, NWH, bin_start, bin_cursor, row_start, NBIN, M, E);
    k_binfill<<<NWF, 256, 0, stream>>>(srcp, dstp, bin_cursor, binned, E);
    k_csr<<<NBIN, 256, 0, stream>>>(binned, bin_start, row_start, dinv, edge_src, M);

    // ---- layer 1: xw16 = fp16((x@W1)*dinv) ; h16 = tanh(b1 + dinv*(self + edges)) ----
    k_gemm_mfma<HID, INDIM, float><<<(M + 63) / 64, 256, 0, stream>>>(x, W1t, dinv, xw16, M);
    k_agg_csr<HID, true, _Float16><<<(M + 15) / 16, 256, 0, stream>>>(row_start, edge_src, xw16, b1, dinv, h16, M);

    // ---- layer 2: hw16 = fp16((h@W2)*dinv) ; out = b2 + dinv*(self + edges) ----
    k_gemm_mfma<OUTD, HID, _Float16><<<(M + 63) / 64, 256, 0, stream>>>(h16, W2t, dinv, hw16, M);
    k_agg_csr<OUTD, false, float><<<(M + 31) / 32, 256, 0, stream>>>(row_start, edge_src, hw16, b2, dinv, out, M);
}